// Round 11
// baseline (142.688 us; speedup 1.0000x reference)
//
#include <hip/hip_runtime.h>

// ConvQuadInterp3d: 3x3x3 replicate-padded stencil, quadratic peak refinement.
// Input  x: FP32, (2,1,10,512,512)
// Output: FP32, coords_max (2,1,3,10,512,512) ++ y_max (2,1,10,512,512)
// Coords channel order: jax source order ch0=d+dx2, ch1=h+dx1, ch2=w+dx0.
// R9: PASSED (absmax 0.0) at dur_us=116, but profile shows quad_kernel < 52us
// (absent from top-5; harness poison fills are 2x53us at HBM ceiling). This
// round: 8 outputs/thread (halves waves, VMEM instrs/output 6.75->4.5,
// halves addressing VALU) + nontemporal stores (84 MB write stream bypasses
// L2). R10 fix: __builtin_nontemporal_store needs a NATIVE vector type —
// HIP's float4 (HIP_vector_type) is rejected; use ext_vector_type(4) float.
//
// NaN discipline: fast-math-safe by construction — keep = |num| <= 0.7*|det|
// evaluated WITHOUT dividing; 1/det only taken when keep (=> det != 0).

constexpr int Dd = 10, Hh = 512, Ww = 512;
constexpr int HW  = Hh * Ww;        // 262144
constexpr int DHW = Dd * HW;        // 2621440
constexpr float BONUS_F = 10.0f;

typedef float vfloat4 __attribute__((ext_vector_type(4)));

__global__ __launch_bounds__(256) void quad_kernel(
        const float* __restrict__ x, float* __restrict__ out) {
    const int tx = threadIdx.x;                 // 0..63 (one wave per row-strip)
    const int w0 = tx << 3;                     // 8 outputs per thread
    const int h  = (blockIdx.y << 2) + threadIdx.y;
    const int bd = blockIdx.z;                  // 0..19: plane index (b*Dd + d)
    const int d  = bd % Dd;
    const int b  = bd / Dd;

    const int pz[3] = { (d == 0) ? bd : bd - 1, bd, (d == Dd - 1) ? bd : bd + 1 };
    const int py[3] = { (h == 0) ? h : h - 1, h, (h == Hh - 1) ? h : h + 1 };
    const int wl = (w0 == 0) ? 0 : w0 - 1;
    const int wr = (w0 + 8 >= Ww) ? (Ww - 1) : (w0 + 8);

    // v[zz][yy][k]: k=0..9 maps to w = w0-1 .. w0+8 (clamped at volume faces)
    float v[3][3][10];
#pragma unroll
    for (int zz = 0; zz < 3; ++zz) {
#pragma unroll
        for (int yy = 0; yy < 3; ++yy) {
            const float* rp = x + (size_t)pz[zz] * HW + (size_t)py[yy] * Ww;
            const float4 c0 = *reinterpret_cast<const float4*>(rp + w0);      // 32B-aligned
            const float4 c1 = *reinterpret_cast<const float4*>(rp + w0 + 4);  // 16B-aligned
            v[zz][yy][0] = rp[wl];
            v[zz][yy][1] = c0.x; v[zz][yy][2] = c0.y;
            v[zz][yy][3] = c0.z; v[zz][yy][4] = c0.w;
            v[zz][yy][5] = c1.x; v[zz][yy][6] = c1.y;
            v[zz][yy][7] = c1.z; v[zz][yy][8] = c1.w;
            v[zz][yy][9] = rp[wr];
        }
    }

    const size_t base = (size_t)d * HW + (size_t)h * Ww + w0;
    float* const p_d = out + ((size_t)(b * 3 + 0)) * DHW + base;
    float* const p_h = out + ((size_t)(b * 3 + 1)) * DHW + base;
    float* const p_w = out + ((size_t)(b * 3 + 2)) * DHW + base;
    float* const p_y = out + (size_t)6 * DHW + (size_t)b * DHW + base;

    float o_d[4], o_h[4], o_w[4], o_y[4];
#pragma unroll
    for (int j = 0; j < 8; ++j) {
        const int k = j + 1;
        const int q = j & 3;                   // slot within the current float4
        const float xc = v[1][1][k];

        // nmax = max(26 neighbors, 0); replicate padding at faces puts the
        // center itself into the neighbor set -> m is false there (matches ref).
        float nm = 0.0f;
#pragma unroll
        for (int zz = 0; zz < 3; ++zz)
#pragma unroll
            for (int yy = 0; yy < 3; ++yy)
#pragma unroll
                for (int dw = -1; dw <= 1; ++dw) {
                    if (zz == 1 && yy == 1 && dw == 0) continue;
                    nm = fmaxf(nm, v[zz][yy][k + dw]);
                }
        const bool m = xc > nm;

        const float gx  = 0.5f * (v[1][1][k + 1] - v[1][1][k - 1]);
        const float gy  = 0.5f * (v[1][2][k] - v[1][0][k]);
        const float gs  = 0.5f * (v[2][1][k] - v[0][1][k]);
        const float dxx = v[1][1][k - 1] + v[1][1][k + 1] - 2.0f * xc;
        const float dyy = v[1][0][k] + v[1][2][k] - 2.0f * xc;
        const float dss = v[0][1][k] + v[2][1][k] - 2.0f * xc;
        const float dxy = 0.25f * (v[1][0][k - 1] + v[1][2][k + 1] - v[1][2][k - 1] - v[1][0][k + 1]);
        const float dys = 0.25f * (v[0][0][k] + v[2][2][k] - v[2][0][k] - v[0][2][k]);
        const float dxs = 0.25f * (v[0][1][k - 1] + v[2][1][k + 1] - v[2][1][k - 1] - v[0][1][k + 1]);

        // Cramer numerators of H*s = g. Rm eps (<=1e-7) dropped: near-singular
        // dets rejected by keep, like ref's far>0.7 clamp of eps-regularized dx.
        const float c00 = dyy * dss - dys * dys;
        const float c01 = dxy * dss - dys * dxs;
        const float c02 = dxy * dys - dyy * dxs;
        const float det = dxx * c00 - dxy * c01 + dxs * c02;
        const float t1  = gy * dss - dys * gs;
        const float t2  = gy * dys - dyy * gs;
        const float t3  = dxy * gs - gy * dxs;
        const float nx = gx * c00 - dxy * t1 + dxs * t2;            // sx * det
        const float ny = dxx * t1 - gx * c01 + dxs * t3;            // sy * det
        const float ns = dxx * (-t2) - dxy * t3 + gx * c02;         // ss * det

        // keep <=> m && det!=0 && all |num/det| <= 0.7, WITHOUT dividing.
        const float lim = 0.7f * fabsf(det);
        const bool keep = m && (fabsf(det) > 0.0f) &&
                          (fabsf(nx) <= lim) && (fabsf(ny) <= lim) && (fabsf(ns) <= lim);
        const float rdet = keep ? (1.0f / det) : 0.0f;
        const float dx0 = -nx * rdet;                   // keep ? -nx/det : 0  (finite)
        const float dx1 = -ny * rdet;
        const float dx2 = -ns * rdet;

        const float dy_ = 0.5f * (gx * dx0 + gy * dx1 + gs * dx2);
        const float y   = xc + dy_ + (m ? BONUS_F : 0.0f);

        o_d[q] = (float)d + dx2;
        o_h[q] = (float)h + dx1;
        o_w[q] = (float)(w0 + j) + dx0;
        o_y[q] = y;

        if (q == 3) {                           // flush a vfloat4 per output array
            const int off = j - 3;              // 0 or 4
            vfloat4 vd = { o_d[0], o_d[1], o_d[2], o_d[3] };
            vfloat4 vh = { o_h[0], o_h[1], o_h[2], o_h[3] };
            vfloat4 vw = { o_w[0], o_w[1], o_w[2], o_w[3] };
            vfloat4 vy = { o_y[0], o_y[1], o_y[2], o_y[3] };
            __builtin_nontemporal_store(vd, reinterpret_cast<vfloat4*>(p_d + off));
            __builtin_nontemporal_store(vh, reinterpret_cast<vfloat4*>(p_h + off));
            __builtin_nontemporal_store(vw, reinterpret_cast<vfloat4*>(p_w + off));
            __builtin_nontemporal_store(vy, reinterpret_cast<vfloat4*>(p_y + off));
        }
    }
}

extern "C" void kernel_launch(void* const* d_in, const int* in_sizes, int n_in,
                              void* d_out, int out_size, void* d_ws, size_t ws_size,
                              hipStream_t stream) {
    (void)in_sizes; (void)n_in; (void)out_size; (void)d_ws; (void)ws_size;
    const float* x = (const float*)d_in[0];
    float* out = (float*)d_out;
    dim3 block(64, 4, 1);
    dim3 grid(1, Hh / 4, 2 * Dd);   // (w-strip, H/4 rows, B*D planes)
    quad_kernel<<<grid, block, 0, stream>>>(x, out);
}

// Round 12
// 117.889 us; speedup vs baseline: 1.2104x; 1.2104x over previous
//
#include <hip/hip_runtime.h>

// ConvQuadInterp3d: 3x3x3 replicate-padded stencil, quadratic peak refinement.
// Input  x: FP32, (2,1,10,512,512)
// Output: FP32, coords_max (2,1,3,10,512,512) ++ y_max (2,1,10,512,512)
// Coords channel order: jax source order ch0=d+dx2, ch1=h+dx1, ch2=w+dx0.
//
// R11 post-mortem: 8-out/thread + NONTEMPORAL stores gave WRITE_SIZE=162MB =
// exactly 2x ideal 84MB. Cause: each lane's two float4 flushes per stream are
// 32B-strided; NT bypasses L2 so half-populated 64B granules hit HBM twice.
// R12: identical kernel with NT removed — stores go through L2, which merges
// the strided halves into full lines. Single-variable change.
//
// NaN discipline: fast-math-safe by construction — keep = |num| <= 0.7*|det|
// evaluated WITHOUT dividing; 1/det only taken when keep (=> det != 0).

constexpr int Dd = 10, Hh = 512, Ww = 512;
constexpr int HW  = Hh * Ww;        // 262144
constexpr int DHW = Dd * HW;        // 2621440
constexpr float BONUS_F = 10.0f;

__global__ __launch_bounds__(256) void quad_kernel(
        const float* __restrict__ x, float* __restrict__ out) {
    const int tx = threadIdx.x;                 // 0..63 (one wave per row-strip)
    const int w0 = tx << 3;                     // 8 outputs per thread
    const int h  = (blockIdx.y << 2) + threadIdx.y;
    const int bd = blockIdx.z;                  // 0..19: plane index (b*Dd + d)
    const int d  = bd % Dd;
    const int b  = bd / Dd;

    const int pz[3] = { (d == 0) ? bd : bd - 1, bd, (d == Dd - 1) ? bd : bd + 1 };
    const int py[3] = { (h == 0) ? h : h - 1, h, (h == Hh - 1) ? h : h + 1 };
    const int wl = (w0 == 0) ? 0 : w0 - 1;
    const int wr = (w0 + 8 >= Ww) ? (Ww - 1) : (w0 + 8);

    // v[zz][yy][k]: k=0..9 maps to w = w0-1 .. w0+8 (clamped at volume faces)
    float v[3][3][10];
#pragma unroll
    for (int zz = 0; zz < 3; ++zz) {
#pragma unroll
        for (int yy = 0; yy < 3; ++yy) {
            const float* rp = x + (size_t)pz[zz] * HW + (size_t)py[yy] * Ww;
            const float4 c0 = *reinterpret_cast<const float4*>(rp + w0);      // 32B-aligned
            const float4 c1 = *reinterpret_cast<const float4*>(rp + w0 + 4);  // 16B-aligned
            v[zz][yy][0] = rp[wl];
            v[zz][yy][1] = c0.x; v[zz][yy][2] = c0.y;
            v[zz][yy][3] = c0.z; v[zz][yy][4] = c0.w;
            v[zz][yy][5] = c1.x; v[zz][yy][6] = c1.y;
            v[zz][yy][7] = c1.z; v[zz][yy][8] = c1.w;
            v[zz][yy][9] = rp[wr];
        }
    }

    const size_t base = (size_t)d * HW + (size_t)h * Ww + w0;
    float* const p_d = out + ((size_t)(b * 3 + 0)) * DHW + base;
    float* const p_h = out + ((size_t)(b * 3 + 1)) * DHW + base;
    float* const p_w = out + ((size_t)(b * 3 + 2)) * DHW + base;
    float* const p_y = out + (size_t)6 * DHW + (size_t)b * DHW + base;

    float o_d[4], o_h[4], o_w[4], o_y[4];
#pragma unroll
    for (int j = 0; j < 8; ++j) {
        const int k = j + 1;
        const int q = j & 3;                   // slot within the current float4
        const float xc = v[1][1][k];

        // nmax = max(26 neighbors, 0); replicate padding at faces puts the
        // center itself into the neighbor set -> m is false there (matches ref).
        float nm = 0.0f;
#pragma unroll
        for (int zz = 0; zz < 3; ++zz)
#pragma unroll
            for (int yy = 0; yy < 3; ++yy)
#pragma unroll
                for (int dw = -1; dw <= 1; ++dw) {
                    if (zz == 1 && yy == 1 && dw == 0) continue;
                    nm = fmaxf(nm, v[zz][yy][k + dw]);
                }
        const bool m = xc > nm;

        const float gx  = 0.5f * (v[1][1][k + 1] - v[1][1][k - 1]);
        const float gy  = 0.5f * (v[1][2][k] - v[1][0][k]);
        const float gs  = 0.5f * (v[2][1][k] - v[0][1][k]);
        const float dxx = v[1][1][k - 1] + v[1][1][k + 1] - 2.0f * xc;
        const float dyy = v[1][0][k] + v[1][2][k] - 2.0f * xc;
        const float dss = v[0][1][k] + v[2][1][k] - 2.0f * xc;
        const float dxy = 0.25f * (v[1][0][k - 1] + v[1][2][k + 1] - v[1][2][k - 1] - v[1][0][k + 1]);
        const float dys = 0.25f * (v[0][0][k] + v[2][2][k] - v[2][0][k] - v[0][2][k]);
        const float dxs = 0.25f * (v[0][1][k - 1] + v[2][1][k + 1] - v[2][1][k - 1] - v[0][1][k + 1]);

        // Cramer numerators of H*s = g. Rm eps (<=1e-7) dropped: near-singular
        // dets rejected by keep, like ref's far>0.7 clamp of eps-regularized dx.
        const float c00 = dyy * dss - dys * dys;
        const float c01 = dxy * dss - dys * dxs;
        const float c02 = dxy * dys - dyy * dxs;
        const float det = dxx * c00 - dxy * c01 + dxs * c02;
        const float t1  = gy * dss - dys * gs;
        const float t2  = gy * dys - dyy * gs;
        const float t3  = dxy * gs - gy * dxs;
        const float nx = gx * c00 - dxy * t1 + dxs * t2;            // sx * det
        const float ny = dxx * t1 - gx * c01 + dxs * t3;            // sy * det
        const float ns = dxx * (-t2) - dxy * t3 + gx * c02;         // ss * det

        // keep <=> m && det!=0 && all |num/det| <= 0.7, WITHOUT dividing.
        const float lim = 0.7f * fabsf(det);
        const bool keep = m && (fabsf(det) > 0.0f) &&
                          (fabsf(nx) <= lim) && (fabsf(ny) <= lim) && (fabsf(ns) <= lim);
        const float rdet = keep ? (1.0f / det) : 0.0f;
        const float dx0 = -nx * rdet;                   // keep ? -nx/det : 0  (finite)
        const float dx1 = -ny * rdet;
        const float dx2 = -ns * rdet;

        const float dy_ = 0.5f * (gx * dx0 + gy * dx1 + gs * dx2);
        const float y   = xc + dy_ + (m ? BONUS_F : 0.0f);

        o_d[q] = (float)d + dx2;
        o_h[q] = (float)h + dx1;
        o_w[q] = (float)(w0 + j) + dx0;
        o_y[q] = y;

        if (q == 3) {                           // flush a float4 per output array
            const int off = j - 3;              // 0 or 4
            *reinterpret_cast<float4*>(p_d + off) = make_float4(o_d[0], o_d[1], o_d[2], o_d[3]);
            *reinterpret_cast<float4*>(p_h + off) = make_float4(o_h[0], o_h[1], o_h[2], o_h[3]);
            *reinterpret_cast<float4*>(p_w + off) = make_float4(o_w[0], o_w[1], o_w[2], o_w[3]);
            *reinterpret_cast<float4*>(p_y + off) = make_float4(o_y[0], o_y[1], o_y[2], o_y[3]);
        }
    }
}

extern "C" void kernel_launch(void* const* d_in, const int* in_sizes, int n_in,
                              void* d_out, int out_size, void* d_ws, size_t ws_size,
                              hipStream_t stream) {
    (void)in_sizes; (void)n_in; (void)out_size; (void)d_ws; (void)ws_size;
    const float* x = (const float*)d_in[0];
    float* out = (float*)d_out;
    dim3 block(64, 4, 1);
    dim3 grid(1, Hh / 4, 2 * Dd);   // (w-strip, H/4 rows, B*D planes)
    quad_kernel<<<grid, block, 0, stream>>>(x, out);
}

// Round 13
// 109.768 us; speedup vs baseline: 1.2999x; 1.0740x over previous
//
#include <hip/hip_runtime.h>

// ConvQuadInterp3d: 3x3x3 replicate-padded stencil, quadratic peak refinement.
// Input  x: FP32, (2,1,10,512,512)
// Output: FP32, coords_max (2,1,3,10,512,512) ++ y_max (2,1,10,512,512)
// Coords channel order: jax source order ch0=d+dx2, ch1=h+dx1, ch2=w+dx0.
//
// R12 post-mortem: constant harness overhead O=74.7us (from R11's measured 68us
// kernel); R9/R12 kernels both ~42us vs 17us ideal traffic. R11 counters:
// VALUBusy 14%, Occupancy 24.5% -> concurrency-starved memory pipeline, writes
// draining at ~2.5-3 TB/s vs fills' 6.4 TB/s on the same buffer. Heavy threads
// (90-float live set, stores bunched at thread end) are the cause.
// R13: ONE output per thread. 27 coalesced scalar loads (L1 absorbs the 3x
// intra-row overlap), ~20-float live set (pure-nmax corner values folded into
// the running max immediately), 5.2M threads = 320 waves/CU -> stores spread
// evenly, max occupancy, deep latency hiding.
//
// NaN discipline: fast-math-safe by construction — keep = |num| <= 0.7*|det|
// evaluated WITHOUT dividing; 1/det only taken when keep (=> det != 0).

constexpr int Dd = 10, Hh = 512, Ww = 512;
constexpr int HW  = Hh * Ww;        // 262144
constexpr int DHW = Dd * HW;        // 2621440
constexpr float BONUS_F = 10.0f;

__global__ __launch_bounds__(256) void quad_kernel(
        const float* __restrict__ x, float* __restrict__ out) {
    const int w  = (blockIdx.x << 6) + threadIdx.x;   // 0..511 (lane = w)
    const int h  = (blockIdx.y << 2) + threadIdx.y;
    const int bd = blockIdx.z;                        // 0..19: b*Dd + d
    const int d  = bd % Dd;
    const int b  = bd / Dd;

    // replicate-clamped neighbor indices
    const int wm = (w == 0) ? 0 : w - 1,      wp = (w == Ww - 1) ? w : w + 1;
    const int hm = (h == 0) ? h : h - 1,      hp = (h == Hh - 1) ? h : h + 1;
    const int zm = (d == 0) ? bd : bd - 1,    zp = (d == Dd - 1) ? bd : bd + 1;

    const float* r0m = x + (size_t)zm * HW + (size_t)hm * Ww;
    const float* r0c = x + (size_t)zm * HW + (size_t)h  * Ww;
    const float* r0p = x + (size_t)zm * HW + (size_t)hp * Ww;
    const float* r1m = x + (size_t)bd * HW + (size_t)hm * Ww;
    const float* r1c = x + (size_t)bd * HW + (size_t)h  * Ww;
    const float* r1p = x + (size_t)bd * HW + (size_t)hp * Ww;
    const float* r2m = x + (size_t)zp * HW + (size_t)hm * Ww;
    const float* r2c = x + (size_t)zp * HW + (size_t)h  * Ww;
    const float* r2p = x + (size_t)zp * HW + (size_t)hp * Ww;

    // nm accumulates the 26-neighbor max (>=0 start). Pure-nmax values
    // (z+-1 plane corners) fold in immediately to keep the live set small.
    float nm = 0.0f;

    // z-1 plane: keep the 5-point cross, fold corners.
    nm = fmaxf(nm, r0m[wm]); nm = fmaxf(nm, r0m[wp]);
    nm = fmaxf(nm, r0p[wm]); nm = fmaxf(nm, r0p[wp]);
    const float p0_01 = r0m[w];                    // (y-1, x)
    const float p0_10 = r0c[wm], p0_11 = r0c[w], p0_12 = r0c[wp];
    const float p0_21 = r0p[w];                    // (y+1, x)
    nm = fmaxf(nm, p0_01); nm = fmaxf(nm, p0_10); nm = fmaxf(nm, p0_11);
    nm = fmaxf(nm, p0_12); nm = fmaxf(nm, p0_21);

    // z+1 plane: same shape.
    nm = fmaxf(nm, r2m[wm]); nm = fmaxf(nm, r2m[wp]);
    nm = fmaxf(nm, r2p[wm]); nm = fmaxf(nm, r2p[wp]);
    const float p2_01 = r2m[w];
    const float p2_10 = r2c[wm], p2_11 = r2c[w], p2_12 = r2c[wp];
    const float p2_21 = r2p[w];
    nm = fmaxf(nm, p2_01); nm = fmaxf(nm, p2_10); nm = fmaxf(nm, p2_11);
    nm = fmaxf(nm, p2_12); nm = fmaxf(nm, p2_21);

    // center plane: all 9 needed for the Hessian.
    const float p1_00 = r1m[wm], p1_01 = r1m[w], p1_02 = r1m[wp];
    const float p1_10 = r1c[wm], xc    = r1c[w], p1_12 = r1c[wp];
    const float p1_20 = r1p[wm], p1_21 = r1p[w], p1_22 = r1p[wp];
    nm = fmaxf(nm, p1_00); nm = fmaxf(nm, p1_01); nm = fmaxf(nm, p1_02);
    nm = fmaxf(nm, p1_10);                        nm = fmaxf(nm, p1_12);
    nm = fmaxf(nm, p1_20); nm = fmaxf(nm, p1_21); nm = fmaxf(nm, p1_22);

    // Replicate padding at faces puts the center into the neighbor set -> m
    // false there (matches ref).
    const bool m = xc > nm;

    const float gx  = 0.5f * (p1_12 - p1_10);
    const float gy  = 0.5f * (p1_21 - p1_01);
    const float gs  = 0.5f * (p2_11 - p0_11);
    const float dxx = p1_10 + p1_12 - 2.0f * xc;
    const float dyy = p1_01 + p1_21 - 2.0f * xc;
    const float dss = p0_11 + p2_11 - 2.0f * xc;
    const float dxy = 0.25f * (p1_00 + p1_22 - p1_20 - p1_02);
    const float dys = 0.25f * (p0_01 + p2_21 - p2_01 - p0_21);
    const float dxs = 0.25f * (p0_10 + p2_12 - p2_10 - p0_12);

    // Cramer numerators of H*s = g. Rm eps (<=1e-7) dropped: near-singular
    // dets rejected by keep, like ref's far>0.7 clamp of eps-regularized dx.
    const float c00 = dyy * dss - dys * dys;
    const float c01 = dxy * dss - dys * dxs;
    const float c02 = dxy * dys - dyy * dxs;
    const float det = dxx * c00 - dxy * c01 + dxs * c02;
    const float t1  = gy * dss - dys * gs;
    const float t2  = gy * dys - dyy * gs;
    const float t3  = dxy * gs - gy * dxs;
    const float nx  = gx * c00 - dxy * t1 + dxs * t2;    // sx * det
    const float ny  = dxx * t1 - gx * c01 + dxs * t3;    // sy * det
    const float ns  = dxx * (-t2) - dxy * t3 + gx * c02; // ss * det

    // keep <=> m && det!=0 && all |num/det| <= 0.7, WITHOUT dividing.
    const float lim = 0.7f * fabsf(det);
    const bool keep = m && (fabsf(det) > 0.0f) &&
                      (fabsf(nx) <= lim) && (fabsf(ny) <= lim) && (fabsf(ns) <= lim);
    const float rdet = keep ? (1.0f / det) : 0.0f;
    const float dx0 = -nx * rdet;                   // keep ? -nx/det : 0  (finite)
    const float dx1 = -ny * rdet;
    const float dx2 = -ns * rdet;

    const float dy_ = 0.5f * (gx * dx0 + gy * dx1 + gs * dx2);
    const float y   = xc + dy_ + (m ? BONUS_F : 0.0f);

    const size_t idx = (size_t)d * HW + (size_t)h * Ww + w;
    out[((size_t)(b * 3 + 0)) * DHW + idx] = (float)d + dx2;
    out[((size_t)(b * 3 + 1)) * DHW + idx] = (float)h + dx1;
    out[((size_t)(b * 3 + 2)) * DHW + idx] = (float)w + dx0;
    out[(size_t)6 * DHW + (size_t)b * DHW + idx] = y;
}

extern "C" void kernel_launch(void* const* d_in, const int* in_sizes, int n_in,
                              void* d_out, int out_size, void* d_ws, size_t ws_size,
                              hipStream_t stream) {
    (void)in_sizes; (void)n_in; (void)out_size; (void)d_ws; (void)ws_size;
    const float* x = (const float*)d_in[0];
    float* out = (float*)d_out;
    dim3 block(64, 4, 1);
    dim3 grid(Ww / 64, Hh / 4, 2 * Dd);   // (8, 128, 20) = 20480 blocks
    quad_kernel<<<grid, block, 0, stream>>>(x, out);
}